// Round 6
// baseline (225.384 us; speedup 1.0000x reference)
//
#include <hip/hip_runtime.h>
#include <hip/hip_bf16.h>

#define VXX 256
#define VYY 256
#define VZZ 20
#define NC  80
#define OH  200
#define OW  200
#define OZ  16
#define SPATIAL (OH*OW*OZ)      // 640000
#define NVOX (VXX*VYY*VZZ)      // 1310720
#define EPSV 1e-5f
#define NS 64                   // spatial positions per block
#define RS 168                  // x_lds row stride in bf16 elems (336 B)
#define NWG (SPATIAL/NS)        // 10000 blocks

typedef float  f32x4 __attribute__((ext_vector_type(4)));
typedef short  s16x8 __attribute__((ext_vector_type(8)));

__device__ __forceinline__ ushort f2bf(float f) {
    uint u = __builtin_bit_cast(uint, f);
    u += 0x7FFFu + ((u >> 16) & 1u);     // round-to-nearest-even
    return (ushort)(u >> 16);
}

__global__ void init_winner_k(int* __restrict__ w) {
    int i = blockIdx.x * 256 + threadIdx.x;
    if (i < NVOX) w[i] = -1;
}

__global__ void scatter_k(const int* __restrict__ coords, int npts,
                          int* __restrict__ winner) {
    int i = blockIdx.x * 256 + threadIdx.x;
    if (i >= npts) return;
    int b = coords[i*4+0];
    int x = coords[i*4+1];
    int y = coords[i*4+2];
    int z = coords[i*4+3];
    int vi = ((b*VXX + x)*VYY + y)*VZZ + z;
    atomicMax(&winner[vi], i);   // max point index == last write wins
}

// Pack W (80x160 fp32) into bf16 MFMA A-fragment order; fold BN into (scale, shift).
// Fragment f = mt*5+ks holds A[o = mt*16 + (l&15)][c = ks*32 + (l>>4)*8 + j].
__global__ void prep_k(const float* __restrict__ wconv,
                       const float* __restrict__ bconv,
                       const float* __restrict__ gamma,
                       const float* __restrict__ beta,
                       const float* __restrict__ mean,
                       const float* __restrict__ var,
                       ushort* __restrict__ wfrag,
                       float2* __restrict__ bnss) {
    int tid = threadIdx.x;
    for (int idx = tid; idx < 25*512; idx += 256) {
        int f   = idx >> 9;
        int rem = idx & 511;
        int l   = rem >> 3;
        int j   = rem & 7;
        int mt  = f / 5;
        int ks  = f - mt*5;
        int o   = mt*16 + (l & 15);
        int c   = ks*32 + (l >> 4)*8 + j;
        wfrag[idx] = f2bf(wconv[o*160 + c]);
    }
    if (tid < NC) {
        float inv = gamma[tid] * rsqrtf(var[tid] + EPSV);
        bnss[tid] = make_float2(inv, bconv[tid]*inv + beta[tid] - mean[tid]*inv);
    }
}

__launch_bounds__(256, 5)
__global__ void fused_k(const float* __restrict__ bev,
                        const float* __restrict__ feats,
                        const int*  __restrict__ winner,
                        const ushort* __restrict__ wfrag,
                        const float2* __restrict__ bnss,
                        float* __restrict__ out) {
    __shared__ __align__(16) ushort x_lds[NS * RS];   // [s][c] bf16, 21 KB

    const int tid   = threadIdx.x;
    // XCD-aware bijective swizzle: 10000 % 8 == 0 -> each XCD gets 1250
    // consecutive tiles (25 full h-rows).
    const int bid   = blockIdx.x;
    const int swzb  = (bid & 7) * (NWG/8) + (bid >> 3);
    const int sbase = swzb * NS;
    const int sl    = tid & 63;         // spatial position within tile
    const int quarter = tid >> 6;       // 0..3 -> 20 prior channels each

    // ---------- Phase A: tap geometry + winner gather ----------
    // (NOTE: 4x redundant across quarters; dedup needs LDS+barrier which would
    //  kill the pre-B load issue — deliberately kept.)
    int   fb_base[8];
    float wk[8];
    {
        const int S = sbase + sl;
        const int z = S & 15;
        const int w = (S >> 4) % OW;
        const int h = S / (OW * OZ);     // uniform within block (3200 % 64 == 0)

        float posy = (h + 0.5f) * ((float)VYY/(float)OH) - 0.5f;
        posy = fminf(fmaxf(posy, 0.f), (float)(VYY-1));
        int y0 = (int)posy; int y1 = min(y0+1, VYY-1); float fy = posy - (float)y0;
        float posx = (w + 0.5f) * ((float)VXX/(float)OW) - 0.5f;
        posx = fminf(fmaxf(posx, 0.f), (float)(VXX-1));
        int x0 = (int)posx; int x1 = min(x0+1, VXX-1); float fx = posx - (float)x0;
        float posz = (z + 0.5f) * ((float)VZZ/(float)OZ) - 0.5f;
        posz = fminf(fmaxf(posz, 0.f), (float)(VZZ-1));
        int z0 = (int)posz; int z1 = min(z0+1, VZZ-1); float fz = posz - (float)z0;

        const int cq = quarter * 5;      // float4 offset within a point's row
        #pragma unroll
        for (int k = 0; k < 8; ++k) {
            int kz = k & 1, kx = (k>>1)&1, ky = k>>2;
            int yy = ky ? y1 : y0, xx = kx ? x1 : x0, zz = kz ? z1 : z0;
            int pi = winner[(xx*VYY + yy)*VZZ + zz];
            float wt = (ky?fy:1.f-fy) * (kx?fx:1.f-fx) * (kz?fz:1.f-fz);
            // Branchless miss handling: read feats row 0 with weight 0
            // (exact: reference's empty voxels contribute 0).
            wk[k]      = (pi < 0) ? 0.f : wt;
            fb_base[k] = ((pi < 0) ? 0 : pi) * 20 + cq;
        }
    }

    // ---------- Phase C prologue: ISSUE q=0 tap batch (8 loads, branchless) ----------
    const float4* feats4 = (const float4*)feats;
    float4 fbA[8], fbB[8];
    #pragma unroll
    for (int k = 0; k < 8; ++k) fbA[k] = feats4[fb_base[k]];

    // ---------- Phase B: bev -> x_lds[s][0..79], shfl-transposed ----------
    // (q=0 gather latency hides under this)
    {
        const int wv = tid >> 6, ln = tid & 63;
        const int q16 = ln & 15, mm = ln >> 4;
        #pragma unroll
        for (int it = 0; it < 5; ++it) {
            int g     = it*4 + wv;          // 0..19 channel-quads
            int cbase = g * 4;              // 0,4,...,76
            const float4 v = *(const float4*)&bev[(cbase+mm)*SPATIAL + sbase + q16*4];
            uint u0 = (uint)f2bf(v.x) | ((uint)f2bf(v.y) << 16);
            uint u1 = (uint)f2bf(v.z) | ((uint)f2bf(v.w) << 16);
            uint us[4];
            #pragma unroll
            for (int j = 0; j < 4; ++j) {
                int src = q16 + 16*j;
                uint t0 = (uint)__shfl((int)u0, src, 64);
                uint t1 = (uint)__shfl((int)u1, src, 64);
                uint sel = (mm & 2) ? t1 : t0;
                us[j] = (mm & 1) ? (sel >> 16) : (sel & 0xffffu);
            }
            uint2 o2 = make_uint2(us[0] | (us[1] << 16), us[2] | (us[3] << 16));
            int row = q16*4 + mm;
            *(uint2*)&x_lds[row*RS + cbase] = o2;
        }
    }

    // ---------- Phase C: branchless 2-buffer pipelined tap gather ----------
    // STEP(q): issue batch q+1 into `nxt`, FMA batch q from `cur`, write bf16.
    {
        const int cbase0 = 80 + quarter*20;
#define GATHER_STEP(CUR, NXT, Q)                                           \
        {                                                                  \
            if ((Q) < 4) {                                                 \
                _Pragma("unroll")                                          \
                for (int k = 0; k < 8; ++k)                                \
                    NXT[k] = feats4[fb_base[k] + (Q) + 1];                 \
            }                                                              \
            float ax=0.f, ay=0.f, az=0.f, aw=0.f;                          \
            _Pragma("unroll")                                              \
            for (int k = 0; k < 8; ++k) {                                  \
                ax += wk[k]*CUR[k].x; ay += wk[k]*CUR[k].y;                \
                az += wk[k]*CUR[k].z; aw += wk[k]*CUR[k].w;                \
            }                                                              \
            ushort4 pk = make_ushort4(f2bf(ax), f2bf(ay),                  \
                                      f2bf(az), f2bf(aw));                 \
            *(ushort4*)&x_lds[sl*RS + cbase0 + (Q)*4] = pk;                \
        }
        GATHER_STEP(fbA, fbB, 0)
        GATHER_STEP(fbB, fbA, 1)
        GATHER_STEP(fbA, fbB, 2)
        GATHER_STEP(fbB, fbA, 3)
        GATHER_STEP(fbA, fbB, 4)
#undef GATHER_STEP
    }

    __syncthreads();

    // ---------- Phase D: MFMA GEMM  y[o][s] = sum_c W[o][c] * x[c][s] ----------
    const int wave = tid >> 6, lane = tid & 63;
    const int lrow = lane & 15, lgrp = lane >> 4;

    f32x4 acc[5];
    #pragma unroll
    for (int mt = 0; mt < 5; ++mt) acc[mt] = (f32x4){0.f, 0.f, 0.f, 0.f};

    const int srow = (wave*16 + lrow) * RS;   // each wave owns a 16-s tile

    #pragma unroll
    for (int ks = 0; ks < 5; ++ks) {
        s16x8 b = *(const s16x8*)&x_lds[srow + ks*32 + lgrp*8];
        #pragma unroll
        for (int mt = 0; mt < 5; ++mt) {
            s16x8 a = *(const s16x8*)&wfrag[((mt*5 + ks)*64 + lane)*8];
            acc[mt] = __builtin_amdgcn_mfma_f32_16x16x32_bf16(a, b, acc[mt], 0, 0, 0);
        }
    }

    // ---------- Epilogue: BN + residual(from LDS bf16) + ReLU ----------
    const int slocal = wave*16 + lrow;
    const int sglob  = sbase + slocal;
    #pragma unroll
    for (int mt = 0; mt < 5; ++mt) {
        #pragma unroll
        for (int r = 0; r < 4; ++r) {
            int o = mt*16 + lgrp*4 + r;
            float2 ss = bnss[o];
            float resid = __builtin_bit_cast(float, (uint)x_lds[slocal*RS + o] << 16);
            float v = acc[mt][r]*ss.x + ss.y + resid;
            out[o*SPATIAL + sglob] = fmaxf(v, 0.f);
        }
    }
}

extern "C" void kernel_launch(void* const* d_in, const int* in_sizes, int n_in,
                              void* d_out, int out_size, void* d_ws, size_t ws_size,
                              hipStream_t stream) {
    const float* bev    = (const float*)d_in[0];
    const int*   coords = (const int*)  d_in[1];
    const float* feats  = (const float*)d_in[2];
    const float* wconv  = (const float*)d_in[3];
    const float* bconv  = (const float*)d_in[4];
    const float* gamma  = (const float*)d_in[5];
    const float* beta   = (const float*)d_in[6];
    const float* mean   = (const float*)d_in[7];
    const float* var    = (const float*)d_in[8];
    float*       out    = (float*)d_out;

    int*    winner = (int*)d_ws;                                      // 5,242,880 B
    ushort* wfrag  = (ushort*)((char*)d_ws + (size_t)NVOX*4);         // 25,600 B
    float2* bnss   = (float2*)((char*)d_ws + (size_t)NVOX*4 + 25600); // 640 B
    int npts = in_sizes[1] / 4;

    hipLaunchKernelGGL(init_winner_k, dim3((NVOX + 255)/256), dim3(256), 0, stream, winner);
    hipLaunchKernelGGL(scatter_k, dim3((npts + 255)/256), dim3(256), 0, stream,
                       coords, npts, winner);
    hipLaunchKernelGGL(prep_k, dim3(1), dim3(256), 0, stream,
                       wconv, bconv, gamma, beta, mean, var, wfrag, bnss);
    hipLaunchKernelGGL(fused_k, dim3(NWG), dim3(256), 0, stream,
                       bev, feats, winner, wfrag, bnss, out);
}

// Round 7
// 190.409 us; speedup vs baseline: 1.1837x; 1.1837x over previous
//
#include <hip/hip_runtime.h>
#include <hip/hip_bf16.h>

#define VXX 256
#define VYY 256
#define VZZ 20
#define NC  80
#define OH  200
#define OW  200
#define OZ  16
#define SPATIAL (OH*OW*OZ)      // 640000
#define NVOX (VXX*VYY*VZZ)      // 1310720
#define EPSV 1e-5f
#define NS 64                   // spatial positions per block
#define RS 168                  // x_lds row stride in bf16 elems (336 B)
#define NWG (SPATIAL/NS)        // 10000 blocks
#define X_FOOT 6                // max distinct x in a block's tap footprint
#define NCELL (2*X_FOOT*VZZ)    // 240 footprint cells
#define SLOTS 64                // staged feats rows (mean occupancy ~34)
#define RSTR 86                 // f32 per row slot (80 + 6 pad) = 344 B

typedef float  f32x4 __attribute__((ext_vector_type(4)));
typedef short  s16x8 __attribute__((ext_vector_type(8)));

__device__ __forceinline__ ushort f2bf(float f) {
    uint u = __builtin_bit_cast(uint, f);
    u += 0x7FFFu + ((u >> 16) & 1u);     // round-to-nearest-even
    return (ushort)(u >> 16);
}

__global__ void init_winner_k(int* __restrict__ w) {
    int i = blockIdx.x * 256 + threadIdx.x;
    if (i < NVOX) w[i] = -1;
}

__global__ void scatter_k(const int* __restrict__ coords, int npts,
                          int* __restrict__ winner) {
    int i = blockIdx.x * 256 + threadIdx.x;
    if (i >= npts) return;
    int b = coords[i*4+0];
    int x = coords[i*4+1];
    int y = coords[i*4+2];
    int z = coords[i*4+3];
    int vi = ((b*VXX + x)*VYY + y)*VZZ + z;
    atomicMax(&winner[vi], i);   // max point index == last write wins
}

// Pack W (80x160 fp32) into bf16 MFMA A-fragment order; fold BN into (scale, shift).
// Fragment f = mt*5+ks holds A[o = mt*16 + (l&15)][c = ks*32 + (l>>4)*8 + j].
__global__ void prep_k(const float* __restrict__ wconv,
                       const float* __restrict__ bconv,
                       const float* __restrict__ gamma,
                       const float* __restrict__ beta,
                       const float* __restrict__ mean,
                       const float* __restrict__ var,
                       ushort* __restrict__ wfrag,
                       float2* __restrict__ bnss) {
    int tid = threadIdx.x;
    for (int idx = tid; idx < 25*512; idx += 256) {
        int f   = idx >> 9;
        int rem = idx & 511;
        int l   = rem >> 3;
        int j   = rem & 7;
        int mt  = f / 5;
        int ks  = f - mt*5;
        int o   = mt*16 + (l & 15);
        int c   = ks*32 + (l >> 4)*8 + j;
        wfrag[idx] = f2bf(wconv[o*160 + c]);
    }
    if (tid < NC) {
        float inv = gamma[tid] * rsqrtf(var[tid] + EPSV);
        bnss[tid] = make_float2(inv, bconv[tid]*inv + beta[tid] - mean[tid]*inv);
    }
}

__launch_bounds__(256, 3)
__global__ void fused_k(const float* __restrict__ bev,
                        const float* __restrict__ feats,
                        const int*  __restrict__ winner,
                        const ushort* __restrict__ wfrag,
                        const float2* __restrict__ bnss,
                        float* __restrict__ out) {
    __shared__ float  rows_lds[SLOTS*RSTR];            // 22016 B, fp32 feats rows
    __shared__ __align__(16) ushort x_lds[NS * RS];    // 21504 B
    __shared__ int    idx_lds[NCELL];                  // 960 B: slot / -1 / -(pi+2)
    __shared__ int    slot_pi[SLOTS];                  // 256 B
    __shared__ int    nslots;

    const int tid   = threadIdx.x;
    const int bid   = blockIdx.x;
    const int swzb  = (bid & 7) * (NWG/8) + (bid >> 3);  // XCD-aware, bijective
    const int sbase = swzb * NS;
    const int sl    = tid & 63;
    const int quarter = tid >> 6;

    // ---------- Block-uniform geometry ----------
    const int h  = sbase / (OW * OZ);
    const int w0 = (sbase >> 4) % OW;     // block spans w0..w0+3, no row crossing
    float posy = (h + 0.5f) * ((float)VYY/(float)OH) - 0.5f;
    posy = fminf(fmaxf(posy, 0.f), (float)(VYY-1));
    const int   y0 = (int)posy;
    const int   y1 = min(y0+1, VYY-1);
    const float fy = posy - (float)y0;
    float posx0 = (w0 + 0.5f) * ((float)VXX/(float)OW) - 0.5f;
    posx0 = fminf(fmaxf(posx0, 0.f), (float)(VXX-1));
    const int xmin = (int)posx0;          // footprint x in [xmin, xmin+5]

    if (tid == 0) nslots = 0;
    __syncthreads();

    // ---------- Phase 1: footprint discovery (coalesced winner reads) ----------
    if (tid < NCELL) {
        int fz  = tid % VZZ;
        int fx  = (tid / VZZ) % X_FOOT;
        int fyc = tid / (VZZ * X_FOOT);
        int xx  = min(xmin + fx, VXX-1);
        int yy  = fyc ? y1 : y0;
        int pi  = winner[(xx*VYY + yy)*VZZ + fz];
        int v   = -1;
        if (pi >= 0) {
            int s = atomicAdd(&nslots, 1);
            if (s < SLOTS) { slot_pi[s] = pi; v = s; }
            else v = -(pi + 2);            // overflow: direct-global fallback
        }
        idx_lds[tid] = v;
    }
    __syncthreads();

    // ---------- Phase 2a: issue feats row loads (4 threads/slot x 5 float4) ----------
    const float4* feats4 = (const float4*)feats;
    const int nst    = min(nslots, SLOTS);
    const int myslot = tid >> 2, part = tid & 3;
    const bool rowact = (myslot < nst);
    float4 rbuf[5];
    if (rowact) {
        const float4* p = feats4 + slot_pi[myslot]*20 + part*5;
        #pragma unroll
        for (int q = 0; q < 5; ++q) rbuf[q] = p[q];
    }

    // ---------- Phase 2b: bev -> x_lds[s][0..79], shfl-transposed ----------
    // (row-load latency hides under this)
    {
        const int wv = tid >> 6, ln = tid & 63;
        const int q16 = ln & 15, mm = ln >> 4;
        #pragma unroll
        for (int it = 0; it < 5; ++it) {
            int g     = it*4 + wv;          // 0..19 channel-quads
            int cbase = g * 4;              // 0,4,...,76
            const float4 v = *(const float4*)&bev[(cbase+mm)*SPATIAL + sbase + q16*4];
            uint u0 = (uint)f2bf(v.x) | ((uint)f2bf(v.y) << 16);
            uint u1 = (uint)f2bf(v.z) | ((uint)f2bf(v.w) << 16);
            uint us[4];
            #pragma unroll
            for (int j = 0; j < 4; ++j) {
                int src = q16 + 16*j;
                uint t0 = (uint)__shfl((int)u0, src, 64);
                uint t1 = (uint)__shfl((int)u1, src, 64);
                uint sel = (mm & 2) ? t1 : t0;
                us[j] = (mm & 1) ? (sel >> 16) : (sel & 0xffffu);
            }
            uint2 o2 = make_uint2(us[0] | (us[1] << 16), us[2] | (us[3] << 16));
            int row = q16*4 + mm;
            *(uint2*)&x_lds[row*RS + cbase] = o2;
        }
    }

    // ---------- Phase 2c: commit feats rows to LDS ----------
    if (rowact) {
        float* dst = &rows_lds[myslot*RSTR + part*20];
        #pragma unroll
        for (int q = 0; q < 5; ++q) {
            *(float2*)&dst[q*4]     = make_float2(rbuf[q].x, rbuf[q].y);
            *(float2*)&dst[q*4 + 2] = make_float2(rbuf[q].z, rbuf[q].w);
        }
    }
    __syncthreads();

    // ---------- Phase 3: LDS-local tap gather -> x_lds[s][80..159] ----------
    {
        const int z = sl & 15;
        const int w = w0 + (sl >> 4);
        float posx = (w + 0.5f) * ((float)VXX/(float)OW) - 0.5f;
        posx = fminf(fmaxf(posx, 0.f), (float)(VXX-1));
        int x0 = (int)posx; int x1 = min(x0+1, VXX-1);
        float fxw = posx - (float)x0;
        float posz = (z + 0.5f) * ((float)VZZ/(float)OZ) - 0.5f;
        posz = fminf(fmaxf(posz, 0.f), (float)(VZZ-1));
        int z0 = (int)posz; int z1 = min(z0+1, VZZ-1);
        float fzw = posz - (float)z0;
        const int fx0 = x0 - xmin, fx1 = x1 - xmin;   // in [0,5]

        f32x4 acc4[5];
        #pragma unroll
        for (int q = 0; q < 5; ++q) acc4[q] = (f32x4){0.f,0.f,0.f,0.f};

        #pragma unroll
        for (int k = 0; k < 8; ++k) {
            int kz = k & 1, kx = (k>>1)&1, ky = k>>2;
            int cell = (ky*X_FOOT + (kx ? fx1 : fx0))*VZZ + (kz ? z1 : z0);
            int v = idx_lds[cell];
            if (v == -1) continue;          // empty voxel: exact +0
            float wtk = (ky?fy:1.f-fy) * (kx?fxw:1.f-fxw) * (kz?fzw:1.f-fzw);
            if (v >= 0) {
                const float* r = &rows_lds[v*RSTR + quarter*20];
                #pragma unroll
                for (int q = 0; q < 5; ++q) {
                    float2 a = *(const float2*)&r[q*4];
                    float2 b = *(const float2*)&r[q*4 + 2];
                    acc4[q][0] += wtk*a.x; acc4[q][1] += wtk*a.y;
                    acc4[q][2] += wtk*b.x; acc4[q][3] += wtk*b.y;
                }
            } else {                         // overflow fallback (cold)
                const float4* p = feats4 + (-v - 2)*20 + quarter*5;
                #pragma unroll
                for (int q = 0; q < 5; ++q) {
                    float4 f = p[q];
                    acc4[q][0] += wtk*f.x; acc4[q][1] += wtk*f.y;
                    acc4[q][2] += wtk*f.z; acc4[q][3] += wtk*f.w;
                }
            }
        }

        #pragma unroll
        for (int q = 0; q < 5; ++q) {
            ushort4 pk = make_ushort4(f2bf(acc4[q][0]), f2bf(acc4[q][1]),
                                      f2bf(acc4[q][2]), f2bf(acc4[q][3]));
            *(ushort4*)&x_lds[sl*RS + 80 + quarter*20 + q*4] = pk;
        }
    }
    __syncthreads();

    // ---------- Phase D: MFMA GEMM  y[o][s] = sum_c W[o][c] * x[c][s] ----------
    const int wave = tid >> 6, lane = tid & 63;
    const int lrow = lane & 15, lgrp = lane >> 4;

    f32x4 acc[5];
    #pragma unroll
    for (int mt = 0; mt < 5; ++mt) acc[mt] = (f32x4){0.f, 0.f, 0.f, 0.f};

    const int srow = (wave*16 + lrow) * RS;   // each wave owns a 16-s tile

    #pragma unroll
    for (int ks = 0; ks < 5; ++ks) {
        s16x8 b = *(const s16x8*)&x_lds[srow + ks*32 + lgrp*8];
        #pragma unroll
        for (int mt = 0; mt < 5; ++mt) {
            s16x8 a = *(const s16x8*)&wfrag[((mt*5 + ks)*64 + lane)*8];
            acc[mt] = __builtin_amdgcn_mfma_f32_16x16x32_bf16(a, b, acc[mt], 0, 0, 0);
        }
    }

    // ---------- Epilogue: BN + residual(from LDS bf16) + ReLU ----------
    const int slocal = wave*16 + lrow;
    const int sglob  = sbase + slocal;
    #pragma unroll
    for (int mt = 0; mt < 5; ++mt) {
        #pragma unroll
        for (int r = 0; r < 4; ++r) {
            int o = mt*16 + lgrp*4 + r;
            float2 ss = bnss[o];
            float resid = __builtin_bit_cast(float, (uint)x_lds[slocal*RS + o] << 16);
            float v = acc[mt][r]*ss.x + ss.y + resid;
            out[o*SPATIAL + sglob] = fmaxf(v, 0.f);
        }
    }
}

extern "C" void kernel_launch(void* const* d_in, const int* in_sizes, int n_in,
                              void* d_out, int out_size, void* d_ws, size_t ws_size,
                              hipStream_t stream) {
    const float* bev    = (const float*)d_in[0];
    const int*   coords = (const int*)  d_in[1];
    const float* feats  = (const float*)d_in[2];
    const float* wconv  = (const float*)d_in[3];
    const float* bconv  = (const float*)d_in[4];
    const float* gamma  = (const float*)d_in[5];
    const float* beta   = (const float*)d_in[6];
    const float* mean   = (const float*)d_in[7];
    const float* var    = (const float*)d_in[8];
    float*       out    = (float*)d_out;

    int*    winner = (int*)d_ws;                                      // 5,242,880 B
    ushort* wfrag  = (ushort*)((char*)d_ws + (size_t)NVOX*4);         // 25,600 B
    float2* bnss   = (float2*)((char*)d_ws + (size_t)NVOX*4 + 25600); // 640 B
    int npts = in_sizes[1] / 4;

    hipLaunchKernelGGL(init_winner_k, dim3((NVOX + 255)/256), dim3(256), 0, stream, winner);
    hipLaunchKernelGGL(scatter_k, dim3((npts + 255)/256), dim3(256), 0, stream,
                       coords, npts, winner);
    hipLaunchKernelGGL(prep_k, dim3(1), dim3(256), 0, stream,
                       wconv, bconv, gamma, beta, mean, var, wfrag, bnss);
    hipLaunchKernelGGL(fused_k, dim3(NWG), dim3(256), 0, stream,
                       bev, feats, winner, wfrag, bnss, out);
}

// Round 8
// 170.133 us; speedup vs baseline: 1.3248x; 1.1192x over previous
//
#include <hip/hip_runtime.h>
#include <hip/hip_bf16.h>

#define VXX 256
#define VYY 256
#define VZZ 20
#define NC  80
#define OH  200
#define OW  200
#define OZ  16
#define SPATIAL (OH*OW*OZ)      // 640000
#define NVOX (VXX*VYY*VZZ)      // 1310720
#define EPSV 1e-5f
#define NS 64                   // spatial positions per block
#define RS 168                  // x_lds row stride in bf16 elems (336 B)
#define NWG (SPATIAL/NS)        // 10000 blocks
#define X_FOOT 6                // max distinct x in a block's tap footprint
#define NCELL (2*X_FOOT*VZZ)    // 240 footprint cells
#define SLOTS 48                // staged feats rows (occupied mean ~37, sd ~5.6)
#define STR32 41                // dwords per row slot (40 data + 1 pad)

typedef float  f32x4 __attribute__((ext_vector_type(4)));
typedef short  s16x8 __attribute__((ext_vector_type(8)));

__device__ __forceinline__ ushort f2bf(float f) {
    uint u = __builtin_bit_cast(uint, f);
    u += 0x7FFFu + ((u >> 16) & 1u);     // round-to-nearest-even
    return (ushort)(u >> 16);
}

__global__ void init_winner_k(int* __restrict__ w) {
    int i = blockIdx.x * 256 + threadIdx.x;
    if (i < NVOX) w[i] = -1;
}

__global__ void scatter_k(const int* __restrict__ coords, int npts,
                          int* __restrict__ winner) {
    int i = blockIdx.x * 256 + threadIdx.x;
    if (i >= npts) return;
    int b = coords[i*4+0];
    int x = coords[i*4+1];
    int y = coords[i*4+2];
    int z = coords[i*4+3];
    int vi = ((b*VXX + x)*VYY + y)*VZZ + z;
    atomicMax(&winner[vi], i);   // max point index == last write wins
}

// Pack W (80x160 fp32) into bf16 MFMA A-fragment order; fold BN into (scale, shift).
// Fragment f = mt*5+ks holds A[o = mt*16 + (l&15)][c = ks*32 + (l>>4)*8 + j].
__global__ void prep_k(const float* __restrict__ wconv,
                       const float* __restrict__ bconv,
                       const float* __restrict__ gamma,
                       const float* __restrict__ beta,
                       const float* __restrict__ mean,
                       const float* __restrict__ var,
                       ushort* __restrict__ wfrag,
                       float2* __restrict__ bnss) {
    int tid = threadIdx.x;
    for (int idx = tid; idx < 25*512; idx += 256) {
        int f   = idx >> 9;
        int rem = idx & 511;
        int l   = rem >> 3;
        int j   = rem & 7;
        int mt  = f / 5;
        int ks  = f - mt*5;
        int o   = mt*16 + (l & 15);
        int c   = ks*32 + (l >> 4)*8 + j;
        wfrag[idx] = f2bf(wconv[o*160 + c]);
    }
    if (tid < NC) {
        float inv = gamma[tid] * rsqrtf(var[tid] + EPSV);
        bnss[tid] = make_float2(inv, bconv[tid]*inv + beta[tid] - mean[tid]*inv);
    }
}

__launch_bounds__(256, 5)
__global__ void fused_k(const float* __restrict__ bev,
                        const float* __restrict__ feats,
                        const int*  __restrict__ winner,
                        const ushort* __restrict__ wfrag,
                        const float2* __restrict__ bnss,
                        float* __restrict__ out) {
    __shared__ __align__(16) ushort x_lds[NS * RS];    // 21504 B
    __shared__ uint   rows_lds[SLOTS*STR32];           // 7872 B, bf16-pair rows
    __shared__ int    idx_lds[NCELL];                  // 960 B: slot / -1 / -(pi+2)
    __shared__ int    slot_pi[SLOTS];                  // 192 B
    __shared__ int    wavecnt[4];                      // 16 B

    const int tid   = threadIdx.x;
    const int bid   = blockIdx.x;
    const int swzb  = (bid & 7) * (NWG/8) + (bid >> 3);  // XCD-aware, bijective
    const int sbase = swzb * NS;
    const int sl    = tid & 63;
    const int quarter = tid >> 6;
    const int wv    = tid >> 6, lane = tid & 63;

    // ---------- Block-uniform geometry ----------
    const int h  = sbase / (OW * OZ);
    const int w0 = (sbase >> 4) % OW;     // block spans w0..w0+3, no row crossing
    float posy = (h + 0.5f) * ((float)VYY/(float)OH) - 0.5f;
    posy = fminf(fmaxf(posy, 0.f), (float)(VYY-1));
    const int   y0 = (int)posy;
    const int   y1 = min(y0+1, VYY-1);
    const float fy = posy - (float)y0;
    float posx0 = (w0 + 0.5f) * ((float)VXX/(float)OW) - 0.5f;
    posx0 = fminf(fmaxf(posx0, 0.f), (float)(VXX-1));
    const int xmin = (int)posx0;          // footprint x in [xmin, xmin+5]

    // ---------- Issue bev loads FIRST (latency hides under discovery) ----------
    float4 bv[5];
    {
        const int q16 = lane & 15, mm = lane >> 4;
        #pragma unroll
        for (int it = 0; it < 5; ++it) {
            int cbase = (it*4 + wv) * 4;    // 0,4,...,76
            bv[it] = *(const float4*)&bev[(cbase+mm)*SPATIAL + sbase + q16*4];
        }
    }

    // ---------- Phase 1: footprint discovery + ballot-scan slot alloc ----------
    int pi = -1;
    if (tid < NCELL) {
        int fz  = tid % VZZ;
        int fx  = (tid / VZZ) % X_FOOT;
        int fyc = tid / (VZZ * X_FOOT);
        int xx  = min(xmin + fx, VXX-1);
        int yy  = fyc ? y1 : y0;
        pi = winner[(xx*VYY + yy)*VZZ + fz];
    }
    unsigned long long bm = __ballot(pi >= 0);
    if (lane == 0) wavecnt[wv] = __popcll(bm);
    __syncthreads();
    int base = 0, nstot = 0;
    #pragma unroll
    for (int w2 = 0; w2 < 4; ++w2) {
        int c2 = wavecnt[w2];
        if (w2 < wv) base += c2;
        nstot += c2;
    }
    if (tid < NCELL) {
        int v = -1;
        if (pi >= 0) {
            int slot = base + __popcll(bm & ((1ull << lane) - 1ull));
            if (slot < SLOTS) { slot_pi[slot] = pi; v = slot; }
            else v = -(pi + 2);            // overflow: direct-global fallback
        }
        idx_lds[tid] = v;
    }
    __syncthreads();
    const int nst = min(nstot, SLOTS);

    // ---------- Phase 2a: issue feats row loads (4 threads/slot x 5 float4) ----------
    const float4* feats4 = (const float4*)feats;
    const int myslot = tid >> 2, part = tid & 3;
    const bool rowact = (myslot < nst);
    float4 rbuf[5];
    if (rowact) {
        const float4* p = feats4 + slot_pi[myslot]*20 + part*5;
        #pragma unroll
        for (int q = 0; q < 5; ++q) rbuf[q] = p[q];
    }

    // ---------- Phase 2b: bev -> x_lds[s][0..79], shfl-transposed ----------
    // (row-load latency hides under this)
    {
        const int q16 = lane & 15, mm = lane >> 4;
        #pragma unroll
        for (int it = 0; it < 5; ++it) {
            int cbase = (it*4 + wv) * 4;
            const float4 v = bv[it];
            uint u0 = (uint)f2bf(v.x) | ((uint)f2bf(v.y) << 16);
            uint u1 = (uint)f2bf(v.z) | ((uint)f2bf(v.w) << 16);
            uint us[4];
            #pragma unroll
            for (int j = 0; j < 4; ++j) {
                int src = q16 + 16*j;
                uint t0 = (uint)__shfl((int)u0, src, 64);
                uint t1 = (uint)__shfl((int)u1, src, 64);
                uint sel = (mm & 2) ? t1 : t0;
                us[j] = (mm & 1) ? (sel >> 16) : (sel & 0xffffu);
            }
            uint2 o2 = make_uint2(us[0] | (us[1] << 16), us[2] | (us[3] << 16));
            int row = q16*4 + mm;
            *(uint2*)&x_lds[row*RS + cbase] = o2;
        }
    }

    // ---------- Phase 2c: commit feats rows to LDS as bf16 pairs ----------
    if (rowact) {
        uint* dst = &rows_lds[myslot*STR32 + part*10];
        #pragma unroll
        for (int q = 0; q < 5; ++q) {
            dst[2*q]   = (uint)f2bf(rbuf[q].x) | ((uint)f2bf(rbuf[q].y) << 16);
            dst[2*q+1] = (uint)f2bf(rbuf[q].z) | ((uint)f2bf(rbuf[q].w) << 16);
        }
    }
    __syncthreads();

    // ---------- Phase 3: LDS-local tap gather -> x_lds[s][80..159] ----------
    {
        const int z = sl & 15;
        const int w = w0 + (sl >> 4);
        float posx = (w + 0.5f) * ((float)VXX/(float)OW) - 0.5f;
        posx = fminf(fmaxf(posx, 0.f), (float)(VXX-1));
        int x0 = (int)posx; int x1 = min(x0+1, VXX-1);
        float fxw = posx - (float)x0;
        float posz = (z + 0.5f) * ((float)VZZ/(float)OZ) - 0.5f;
        posz = fminf(fmaxf(posz, 0.f), (float)(VZZ-1));
        int z0 = (int)posz; int z1 = min(z0+1, VZZ-1);
        float fzw = posz - (float)z0;
        const int fx0 = x0 - xmin, fx1 = x1 - xmin;   // in [0,5]

        float acc20[20];
        #pragma unroll
        for (int j = 0; j < 20; ++j) acc20[j] = 0.f;

        #pragma unroll
        for (int k = 0; k < 8; ++k) {
            int kz = k & 1, kx = (k>>1)&1, ky = k>>2;
            int cell = (ky*X_FOOT + (kx ? fx1 : fx0))*VZZ + (kz ? z1 : z0);
            int v = idx_lds[cell];
            if (v == -1) continue;          // empty voxel: exact +0
            float wtk = (ky?fy:1.f-fy) * (kx?fxw:1.f-fxw) * (kz?fzw:1.f-fzw);
            if (v >= 0) {
                const uint* r = &rows_lds[v*STR32 + quarter*10];
                #pragma unroll
                for (int qq = 0; qq < 10; ++qq) {
                    uint u = r[qq];
                    float lo = __builtin_bit_cast(float, u << 16);
                    float hi = __builtin_bit_cast(float, u & 0xffff0000u);
                    acc20[2*qq]   += wtk * lo;
                    acc20[2*qq+1] += wtk * hi;
                }
            } else {                         // overflow fallback (cold)
                const float4* p = feats4 + (-v - 2)*20 + quarter*5;
                #pragma unroll
                for (int q = 0; q < 5; ++q) {
                    float4 f = p[q];
                    acc20[4*q]   += wtk*f.x; acc20[4*q+1] += wtk*f.y;
                    acc20[4*q+2] += wtk*f.z; acc20[4*q+3] += wtk*f.w;
                }
            }
        }

        #pragma unroll
        for (int q = 0; q < 5; ++q) {
            ushort4 pk = make_ushort4(f2bf(acc20[4*q]),   f2bf(acc20[4*q+1]),
                                      f2bf(acc20[4*q+2]), f2bf(acc20[4*q+3]));
            *(ushort4*)&x_lds[sl*RS + 80 + quarter*20 + q*4] = pk;
        }
    }
    __syncthreads();

    // ---------- Phase D: MFMA GEMM  y[o][s] = sum_c W[o][c] * x[c][s] ----------
    const int lrow = lane & 15, lgrp = lane >> 4;

    f32x4 acc[5];
    #pragma unroll
    for (int mt = 0; mt < 5; ++mt) acc[mt] = (f32x4){0.f, 0.f, 0.f, 0.f};

    const int srow = (wv*16 + lrow) * RS;   // each wave owns a 16-s tile

    #pragma unroll
    for (int ks = 0; ks < 5; ++ks) {
        s16x8 b = *(const s16x8*)&x_lds[srow + ks*32 + lgrp*8];
        #pragma unroll
        for (int mt = 0; mt < 5; ++mt) {
            s16x8 a = *(const s16x8*)&wfrag[((mt*5 + ks)*64 + lane)*8];
            acc[mt] = __builtin_amdgcn_mfma_f32_16x16x32_bf16(a, b, acc[mt], 0, 0, 0);
        }
    }

    // ---------- Epilogue: BN + residual(from LDS bf16) + ReLU ----------
    const int slocal = wv*16 + lrow;
    const int sglob  = sbase + slocal;
    #pragma unroll
    for (int mt = 0; mt < 5; ++mt) {
        #pragma unroll
        for (int r = 0; r < 4; ++r) {
            int o = mt*16 + lgrp*4 + r;
            float2 ss = bnss[o];
            float resid = __builtin_bit_cast(float, (uint)x_lds[slocal*RS + o] << 16);
            float v = acc[mt][r]*ss.x + ss.y + resid;
            out[o*SPATIAL + sglob] = fmaxf(v, 0.f);
        }
    }
}

extern "C" void kernel_launch(void* const* d_in, const int* in_sizes, int n_in,
                              void* d_out, int out_size, void* d_ws, size_t ws_size,
                              hipStream_t stream) {
    const float* bev    = (const float*)d_in[0];
    const int*   coords = (const int*)  d_in[1];
    const float* feats  = (const float*)d_in[2];
    const float* wconv  = (const float*)d_in[3];
    const float* bconv  = (const float*)d_in[4];
    const float* gamma  = (const float*)d_in[5];
    const float* beta   = (const float*)d_in[6];
    const float* mean   = (const float*)d_in[7];
    const float* var    = (const float*)d_in[8];
    float*       out    = (float*)d_out;

    int*    winner = (int*)d_ws;                                      // 5,242,880 B
    ushort* wfrag  = (ushort*)((char*)d_ws + (size_t)NVOX*4);         // 25,600 B
    float2* bnss   = (float2*)((char*)d_ws + (size_t)NVOX*4 + 25600); // 640 B
    int npts = in_sizes[1] / 4;

    hipLaunchKernelGGL(init_winner_k, dim3((NVOX + 255)/256), dim3(256), 0, stream, winner);
    hipLaunchKernelGGL(scatter_k, dim3((npts + 255)/256), dim3(256), 0, stream,
                       coords, npts, winner);
    hipLaunchKernelGGL(prep_k, dim3(1), dim3(256), 0, stream,
                       wconv, bconv, gamma, beta, mean, var, wfrag, bnss);
    hipLaunchKernelGGL(fused_k, dim3(NWG), dim3(256), 0, stream,
                       bev, feats, winner, wfrag, bnss, out);
}

// Round 9
// 153.238 us; speedup vs baseline: 1.4708x; 1.1103x over previous
//
#include <hip/hip_runtime.h>
#include <hip/hip_bf16.h>

#define VXX 256
#define VYY 256
#define VZZ 20
#define NC  80
#define OH  200
#define OW  200
#define OZ  16
#define SPATIAL (OH*OW*OZ)      // 640000
#define NVOX (VXX*VYY*VZZ)      // 1310720
#define EPSV 1e-5f
#define NS 64                   // spatial positions per block
#define RS 168                  // x_lds row stride in bf16 elems (336 B)
#define NWG (SPATIAL/NS)        // 10000 blocks
#define X_FOOT 6                // max distinct x in a block's tap footprint
#define NCELL (2*X_FOOT*VZZ)    // 240 footprint cells
#define SLOTS 48                // staged feats rows (occupied mean ~34, sd ~5.4)
#define STR32 41                // dwords per row slot (40 data + 1 pad)

typedef float  f32x4 __attribute__((ext_vector_type(4)));
typedef short  s16x8 __attribute__((ext_vector_type(8)));

__device__ __forceinline__ ushort f2bf(float f) {
    uint u = __builtin_bit_cast(uint, f);
    u += 0x7FFFu + ((u >> 16) & 1u);     // round-to-nearest-even
    return (ushort)(u >> 16);
}

// Barrier that drains ONLY LDS ops (all cross-thread deps in fused_k are LDS).
// Avoids the vmcnt(0) drain __syncthreads() implies, keeping global loads in flight.
__device__ __forceinline__ void bar_lgkm() {
    asm volatile("s_waitcnt lgkmcnt(0)" ::: "memory");
    __builtin_amdgcn_s_barrier();
    asm volatile("" ::: "memory");
}

__global__ void scatter_k(const int* __restrict__ coords, int npts,
                          int* __restrict__ winner) {
    int i = blockIdx.x * 256 + threadIdx.x;
    if (i >= npts) return;
    int b = coords[i*4+0];
    int x = coords[i*4+1];
    int y = coords[i*4+2];
    int z = coords[i*4+3];
    int vi = ((b*VXX + x)*VYY + y)*VZZ + z;
    atomicMax(&winner[vi], i);   // max point index == last write wins
}

// Merged: winner init (blocks 0..1279), W-fragment pack (1280..1329), BN fold (1330).
__global__ void setup_k(const float* __restrict__ wconv,
                        const float* __restrict__ bconv,
                        const float* __restrict__ gamma,
                        const float* __restrict__ beta,
                        const float* __restrict__ mean,
                        const float* __restrict__ var,
                        int4* __restrict__ winner4,
                        ushort* __restrict__ wfrag,
                        float2* __restrict__ bnss) {
    const int b = blockIdx.x, tid = threadIdx.x;
    if (b < 1280) {
        winner4[b*256 + tid] = make_int4(-1, -1, -1, -1);   // NVOX/4 = 327680
    } else if (b < 1330) {
        int idx = (b - 1280)*256 + tid;    // < 12800
        int f   = idx >> 9;
        int rem = idx & 511;
        int l   = rem >> 3;
        int j   = rem & 7;
        int mt  = f / 5;
        int ks  = f - mt*5;
        int o   = mt*16 + (l & 15);
        int c   = ks*32 + (l >> 4)*8 + j;
        wfrag[idx] = f2bf(wconv[o*160 + c]);
    } else if (tid < NC) {
        float inv = gamma[tid] * rsqrtf(var[tid] + EPSV);
        bnss[tid] = make_float2(inv, bconv[tid]*inv + beta[tid] - mean[tid]*inv);
    }
}

__launch_bounds__(256, 5)
__global__ void fused_k(const float* __restrict__ bev,
                        const float* __restrict__ feats,
                        const int*  __restrict__ winner,
                        const ushort* __restrict__ wfrag,
                        const float2* __restrict__ bnss,
                        float* __restrict__ out) {
    __shared__ __align__(16) ushort x_lds[NS * RS];    // 21504 B
    __shared__ uint   rows_lds[SLOTS*STR32];           // 7872 B, bf16-pair rows
    __shared__ int    idx_lds[NCELL];                  // 960 B: slot / -1 / -(pi+2)
    __shared__ int    slot_pi[SLOTS];                  // 192 B
    __shared__ int    wavecnt[4];                      // 16 B

    const int tid   = threadIdx.x;
    const int bid   = blockIdx.x;
    const int swzb  = (bid & 7) * (NWG/8) + (bid >> 3);  // XCD-aware, bijective
    const int sbase = swzb * NS;
    const int sl    = tid & 63;
    const int quarter = tid >> 6;
    const int wv    = quarter, lane = sl;

    // ---------- Block-uniform geometry ----------
    const int h  = sbase / (OW * OZ);
    const int w0 = (sbase >> 4) % OW;     // block spans w0..w0+3, no row crossing
    float posy = (h + 0.5f) * ((float)VYY/(float)OH) - 0.5f;
    posy = fminf(fmaxf(posy, 0.f), (float)(VYY-1));
    const int   y0 = (int)posy;
    const int   y1 = min(y0+1, VYY-1);
    const float fy = posy - (float)y0;
    float posx0 = (w0 + 0.5f) * ((float)VXX/(float)OW) - 0.5f;
    posx0 = fminf(fmaxf(posx0, 0.f), (float)(VXX-1));
    const int xmin = (int)posx0;          // footprint x in [xmin, xmin+5]

    // ---------- Issue winner load FIRST (oldest in vmem queue) ----------
    int pi = -1;
    if (tid < NCELL) {
        int fz  = tid % VZZ;
        int fx  = (tid / VZZ) % X_FOOT;
        int fyc = tid / (VZZ * X_FOOT);
        int xx  = min(xmin + fx, VXX-1);
        int yy  = fyc ? y1 : y0;
        pi = winner[(xx*VYY + yy)*VZZ + fz];
    }
    __builtin_amdgcn_sched_barrier(0);    // keep winner load ahead of bev loads

    // ---------- Issue bev loads: 20 scalar coalesced dwords (lane = s) ----------
    // Consuming `pi` below waits vmcnt(20) -> only the winner load, not these.
    const int S = sbase + sl;
    float bvv[20];
    #pragma unroll
    for (int j = 0; j < 20; ++j)
        bvv[j] = bev[(quarter*20 + j)*SPATIAL + S];
    __builtin_amdgcn_sched_barrier(0);    // pin loads above the ballot/barriers

    // ---------- Phase 1: ballot-scan slot allocation ----------
    unsigned long long bm = __ballot(pi >= 0);
    if (lane == 0) wavecnt[wv] = __popcll(bm);
    bar_lgkm();
    int base = 0, nstot = 0;
    #pragma unroll
    for (int w2 = 0; w2 < 4; ++w2) {
        int c2 = wavecnt[w2];
        if (w2 < wv) base += c2;
        nstot += c2;
    }
    if (tid < NCELL) {
        int v = -1;
        if (pi >= 0) {
            int slot = base + __popcll(bm & ((1ull << lane) - 1ull));
            if (slot < SLOTS) { slot_pi[slot] = pi; v = slot; }
            else v = -(pi + 2);            // overflow: direct-global fallback
        }
        idx_lds[tid] = v;
    }
    bar_lgkm();
    const int nst = min(nstot, SLOTS);

    // ---------- Phase 2a: issue feats row loads (4 threads/slot x 5 float4) ----------
    const float4* feats4 = (const float4*)feats;
    const int myslot = tid >> 2, part = tid & 3;
    const bool rowact = (myslot < nst);
    float4 rbuf[5];
    if (rowact) {
        const float4* p = feats4 + slot_pi[myslot]*20 + part*5;
        #pragma unroll
        for (int q = 0; q < 5; ++q) rbuf[q] = p[q];
    }

    // ---------- Phase 2b: stage bev -> x_lds[s][0..79] (no transpose needed) ----------
    #pragma unroll
    for (int j5 = 0; j5 < 5; ++j5) {
        ushort4 pk = make_ushort4(f2bf(bvv[j5*4+0]), f2bf(bvv[j5*4+1]),
                                  f2bf(bvv[j5*4+2]), f2bf(bvv[j5*4+3]));
        *(ushort4*)&x_lds[sl*RS + quarter*20 + j5*4] = pk;
    }

    // ---------- Phase 2c: commit feats rows to LDS as bf16 pairs ----------
    if (rowact) {
        uint* dst = &rows_lds[myslot*STR32 + part*10];
        #pragma unroll
        for (int q = 0; q < 5; ++q) {
            dst[2*q]   = (uint)f2bf(rbuf[q].x) | ((uint)f2bf(rbuf[q].y) << 16);
            dst[2*q+1] = (uint)f2bf(rbuf[q].z) | ((uint)f2bf(rbuf[q].w) << 16);
        }
    }
    bar_lgkm();

    // ---------- Phase 3: LDS-local tap gather -> x_lds[s][80..159] ----------
    {
        const int z = sl & 15;
        const int w = w0 + (sl >> 4);
        float posx = (w + 0.5f) * ((float)VXX/(float)OW) - 0.5f;
        posx = fminf(fmaxf(posx, 0.f), (float)(VXX-1));
        int x0 = (int)posx; int x1 = min(x0+1, VXX-1);
        float fxw = posx - (float)x0;
        float posz = (z + 0.5f) * ((float)VZZ/(float)OZ) - 0.5f;
        posz = fminf(fmaxf(posz, 0.f), (float)(VZZ-1));
        int z0 = (int)posz; int z1 = min(z0+1, VZZ-1);
        float fzw = posz - (float)z0;
        const int fx0 = x0 - xmin, fx1 = x1 - xmin;   // in [0,5]

        float acc20[20];
        #pragma unroll
        for (int j = 0; j < 20; ++j) acc20[j] = 0.f;

        #pragma unroll
        for (int k = 0; k < 8; ++k) {
            int kz = k & 1, kx = (k>>1)&1, ky = k>>2;
            int cell = (ky*X_FOOT + (kx ? fx1 : fx0))*VZZ + (kz ? z1 : z0);
            int v = idx_lds[cell];
            if (v == -1) continue;          // empty voxel: exact +0
            float wtk = (ky?fy:1.f-fy) * (kx?fxw:1.f-fxw) * (kz?fzw:1.f-fzw);
            if (v >= 0) {
                const uint* r = &rows_lds[v*STR32 + quarter*10];
                #pragma unroll
                for (int qq = 0; qq < 10; ++qq) {
                    uint u = r[qq];
                    float lo = __builtin_bit_cast(float, u << 16);
                    float hi = __builtin_bit_cast(float, u & 0xffff0000u);
                    acc20[2*qq]   += wtk * lo;
                    acc20[2*qq+1] += wtk * hi;
                }
            } else {                         // overflow fallback (cold)
                const float4* p = feats4 + (-v - 2)*20 + quarter*5;
                #pragma unroll
                for (int q = 0; q < 5; ++q) {
                    float4 f = p[q];
                    acc20[4*q]   += wtk*f.x; acc20[4*q+1] += wtk*f.y;
                    acc20[4*q+2] += wtk*f.z; acc20[4*q+3] += wtk*f.w;
                }
            }
        }

        #pragma unroll
        for (int q = 0; q < 5; ++q) {
            ushort4 pk = make_ushort4(f2bf(acc20[4*q]),   f2bf(acc20[4*q+1]),
                                      f2bf(acc20[4*q+2]), f2bf(acc20[4*q+3]));
            *(ushort4*)&x_lds[sl*RS + 80 + quarter*20 + q*4] = pk;
        }
    }
    bar_lgkm();

    // ---------- Phase D: MFMA GEMM  y[o][s] = sum_c W[o][c] * x[c][s] ----------
    const int lrow = lane & 15, lgrp = lane >> 4;

    f32x4 acc[5];
    #pragma unroll
    for (int mt = 0; mt < 5; ++mt) acc[mt] = (f32x4){0.f, 0.f, 0.f, 0.f};

    const int srow = (wv*16 + lrow) * RS;   // each wave owns a 16-s tile

    #pragma unroll
    for (int ks = 0; ks < 5; ++ks) {
        s16x8 b = *(const s16x8*)&x_lds[srow + ks*32 + lgrp*8];
        #pragma unroll
        for (int mt = 0; mt < 5; ++mt) {
            s16x8 a = *(const s16x8*)&wfrag[((mt*5 + ks)*64 + lane)*8];
            acc[mt] = __builtin_amdgcn_mfma_f32_16x16x32_bf16(a, b, acc[mt], 0, 0, 0);
        }
    }

    // ---------- Epilogue: BN + residual (batched b64 LDS read) + ReLU ----------
    const int slocal = wv*16 + lrow;
    const int sglob  = sbase + slocal;
    #pragma unroll
    for (int mt = 0; mt < 5; ++mt) {
        ushort4 rr = *(const ushort4*)&x_lds[slocal*RS + mt*16 + lgrp*4];
        const ushort rrv[4] = {rr.x, rr.y, rr.z, rr.w};
        #pragma unroll
        for (int r = 0; r < 4; ++r) {
            int o = mt*16 + lgrp*4 + r;
            float2 ss = bnss[o];
            float resid = __builtin_bit_cast(float, (uint)rrv[r] << 16);
            float v = acc[mt][r]*ss.x + ss.y + resid;
            out[o*SPATIAL + sglob] = fmaxf(v, 0.f);
        }
    }
}

extern "C" void kernel_launch(void* const* d_in, const int* in_sizes, int n_in,
                              void* d_out, int out_size, void* d_ws, size_t ws_size,
                              hipStream_t stream) {
    const float* bev    = (const float*)d_in[0];
    const int*   coords = (const int*)  d_in[1];
    const float* feats  = (const float*)d_in[2];
    const float* wconv  = (const float*)d_in[3];
    const float* bconv  = (const float*)d_in[4];
    const float* gamma  = (const float*)d_in[5];
    const float* beta   = (const float*)d_in[6];
    const float* mean   = (const float*)d_in[7];
    const float* var    = (const float*)d_in[8];
    float*       out    = (float*)d_out;

    int*    winner = (int*)d_ws;                                      // 5,242,880 B
    ushort* wfrag  = (ushort*)((char*)d_ws + (size_t)NVOX*4);         // 25,600 B
    float2* bnss   = (float2*)((char*)d_ws + (size_t)NVOX*4 + 25600); // 640 B
    int npts = in_sizes[1] / 4;

    hipLaunchKernelGGL(setup_k, dim3(1331), dim3(256), 0, stream,
                       wconv, bconv, gamma, beta, mean, var,
                       (int4*)winner, wfrag, bnss);
    hipLaunchKernelGGL(scatter_k, dim3((npts + 255)/256), dim3(256), 0, stream,
                       coords, npts, winner);
    hipLaunchKernelGGL(fused_k, dim3(NWG), dim3(256), 0, stream,
                       bev, feats, winner, wfrag, bnss, out);
}

// Round 12
// 149.254 us; speedup vs baseline: 1.5101x; 1.0267x over previous
//
#include <hip/hip_runtime.h>
#include <hip/hip_bf16.h>

#define VXX 256
#define VYY 256
#define VZZ 20
#define NC  80
#define OH  200
#define OW  200
#define OZ  16
#define SPATIAL (OH*OW*OZ)      // 640000
#define NVOX (VXX*VYY*VZZ)      // 1310720
#define EPSV 1e-5f
#define NS 64                   // spatial positions per block
#define RS 168                  // x_lds row stride in bf16 elems (336 B)
#define NWG (SPATIAL/NS)        // 10000 blocks
#define X_FOOT 6                // max distinct x in a block's tap footprint
#define NCELL (2*X_FOOT*VZZ)    // 240 footprint cells
#define SLOTS 48                // staged feats rows (occupied mean ~34, sd ~5.4)
#define PSTR 72                 // bf16 per P/Rt row (64 K + 8 pad; 144 B, 16B-aligned)

typedef float  f32x4 __attribute__((ext_vector_type(4)));
typedef short  s16x8 __attribute__((ext_vector_type(8)));

__device__ __forceinline__ ushort f2bf(float f) {
    uint u = __builtin_bit_cast(uint, f);
    u += 0x7FFFu + ((u >> 16) & 1u);     // round-to-nearest-even
    return (ushort)(u >> 16);
}

// Barrier that drains ONLY LDS ops (all cross-thread deps in fused_k are LDS).
__device__ __forceinline__ void bar_lgkm() {
    asm volatile("s_waitcnt lgkmcnt(0)" ::: "memory");
    __builtin_amdgcn_s_barrier();
    asm volatile("" ::: "memory");
}

__global__ void scatter_k(const int* __restrict__ coords, int npts,
                          int* __restrict__ winner) {
    int i = blockIdx.x * 256 + threadIdx.x;
    if (i >= npts) return;
    int b = coords[i*4+0];
    int x = coords[i*4+1];
    int y = coords[i*4+2];
    int z = coords[i*4+3];
    int vi = ((b*VXX + x)*VYY + y)*VZZ + z;
    atomicMax(&winner[vi], i);   // max point index == last write wins
}

// Merged: winner init (blocks 0..1279), W-fragment pack (1280..1329), BN fold (1330).
__global__ void setup_k(const float* __restrict__ wconv,
                        const float* __restrict__ bconv,
                        const float* __restrict__ gamma,
                        const float* __restrict__ beta,
                        const float* __restrict__ mean,
                        const float* __restrict__ var,
                        int4* __restrict__ winner4,
                        ushort* __restrict__ wfrag,
                        float2* __restrict__ bnss) {
    const int b = blockIdx.x, tid = threadIdx.x;
    if (b < 1280) {
        winner4[b*256 + tid] = make_int4(-1, -1, -1, -1);   // NVOX/4 = 327680
    } else if (b < 1330) {
        int idx = (b - 1280)*256 + tid;    // < 12800
        int f   = idx >> 9;
        int rem = idx & 511;
        int l   = rem >> 3;
        int j   = rem & 7;
        int mt  = f / 5;
        int ks  = f - mt*5;
        int o   = mt*16 + (l & 15);
        int c   = ks*32 + (l >> 4)*8 + j;
        wfrag[idx] = f2bf(wconv[o*160 + c]);
    } else if (tid < NC) {
        float inv = gamma[tid] * rsqrtf(var[tid] + EPSV);
        bnss[tid] = make_float2(inv, bconv[tid]*inv + beta[tid] - mean[tid]*inv);
    }
}

__launch_bounds__(256, 3)
__global__ void fused_k(const float* __restrict__ bev,
                        const float* __restrict__ feats,
                        const int*  __restrict__ winner,
                        const ushort* __restrict__ wfrag,
                        const float2* __restrict__ bnss,
                        float* __restrict__ out) {
    __shared__ __align__(16) ushort x_lds[NS * RS];     // 21504 B
    __shared__ __align__(16) ushort P_lds[NS * PSTR];   //  9216 B: tap weights [s][slot]
    __shared__ __align__(16) ushort Rt_lds[NC * PSTR];  // 11520 B: feats rows  [c][slot]
    __shared__ int    idx_lds[NCELL];                   //   960 B: slot / -1 / -(pi+2)
    __shared__ int    slot_pi[SLOTS];                   //   192 B
    __shared__ int    wavecnt[4];                       //    16 B

    const int tid   = threadIdx.x;
    const int bid   = blockIdx.x;
    const int swzb  = (bid & 7) * (NWG/8) + (bid >> 3);  // XCD-aware, bijective
    const int sbase = swzb * NS;
    const int sl    = tid & 63;
    const int quarter = tid >> 6;
    const int wv    = quarter, lane = sl;

    // ---------- Block-uniform geometry ----------
    const int h  = sbase / (OW * OZ);
    const int w0 = (sbase >> 4) % OW;     // block spans w0..w0+3, no row crossing
    float posy = (h + 0.5f) * ((float)VYY/(float)OH) - 0.5f;
    posy = fminf(fmaxf(posy, 0.f), (float)(VYY-1));
    const int   y0 = (int)posy;
    const int   y1 = min(y0+1, VYY-1);
    const float fy = posy - (float)y0;
    float posx0 = (w0 + 0.5f) * ((float)VXX/(float)OW) - 0.5f;
    posx0 = fminf(fmaxf(posx0, 0.f), (float)(VXX-1));
    const int xmin = (int)posx0;          // footprint x in [xmin, xmin+5]

    // ---------- Per-thread (s) tap geometry ----------
    const int zq = sl & 15;
    const int wq = w0 + (sl >> 4);
    float posx = (wq + 0.5f) * ((float)VXX/(float)OW) - 0.5f;
    posx = fminf(fmaxf(posx, 0.f), (float)(VXX-1));
    const int   x0 = (int)posx;
    const int   x1 = min(x0+1, VXX-1);
    const float fxw = posx - (float)x0;
    float posz = (zq + 0.5f) * ((float)VZZ/(float)OZ) - 0.5f;
    posz = fminf(fmaxf(posz, 0.f), (float)(VZZ-1));
    const int   z0 = (int)posz;
    const int   z1 = min(z0+1, VZZ-1);
    const float fzw = posz - (float)z0;
    const int fx0 = x0 - xmin, fx1 = x1 - xmin;   // in [0,5]

    // ---------- Issue winner load FIRST (oldest in vmem queue) ----------
    int pi = -1;
    if (tid < NCELL) {
        int fz  = tid % VZZ;
        int fx  = (tid / VZZ) % X_FOOT;
        int fyc = tid / (VZZ * X_FOOT);
        int xx  = min(xmin + fx, VXX-1);
        int yy  = fyc ? y1 : y0;
        pi = winner[(xx*VYY + yy)*VZZ + fz];
    }
    __builtin_amdgcn_sched_barrier(0);    // keep winner load ahead of bev loads

    // ---------- Issue bev loads: 20 scalar coalesced dwords (lane = s) ----------
    const int S = sbase + sl;
    float bvv[20];
    #pragma unroll
    for (int j = 0; j < 20; ++j)
        bvv[j] = bev[(quarter*20 + j)*SPATIAL + S];
    __builtin_amdgcn_sched_barrier(0);    // pin loads above the ballot/barriers

    // ---------- P zero (hides under winner latency) ----------
    {
        uint* pz = (uint*)P_lds;          // 2304 dwords
        #pragma unroll
        for (int i = 0; i < 9; ++i) pz[tid + i*256] = 0;
    }

    // ---------- Phase 1: ballot-scan slot allocation ----------
    unsigned long long bm = __ballot(pi >= 0);
    if (lane == 0) wavecnt[wv] = __popcll(bm);
    bar_lgkm();
    int base = 0, nstot = 0;
    #pragma unroll
    for (int w2 = 0; w2 < 4; ++w2) {
        int c2 = wavecnt[w2];
        if (w2 < wv) base += c2;
        nstot += c2;
    }
    if (tid < NCELL) {
        int v = -1;
        if (pi >= 0) {
            int slot = base + __popcll(bm & ((1ull << lane) - 1ull));
            if (slot < SLOTS) { slot_pi[slot] = pi; v = slot; }
            else v = -(pi + 2);            // overflow: direct-global fallback
        }
        idx_lds[tid] = v;
    }
    bar_lgkm();
    const int nst = min(nstot, SLOTS);

    // ---------- Phase 2a: issue feats row loads (4 threads/slot x 5 float4) ----------
    const float4* feats4 = (const float4*)feats;
    const int myslot = tid >> 2, part = tid & 3;   // myslot 0..63
    const bool rowact = (myslot < nst);
    float4 rbuf[5];
    if (rowact) {
        const float4* p = feats4 + slot_pi[myslot]*20 + part*5;
        #pragma unroll
        for (int q = 0; q < 5; ++q) rbuf[q] = p[q];
    }

    // ---------- Phase 2b: P scatter (thread (s, quarter) owns taps 2q, 2q+1) ----------
    {
        const int ky = quarter >> 1, kx = quarter & 1;
        const float ywp = ky ? fy : 1.f - fy;
        const bool xdup = (fx1 == fx0);   // statically never at these shapes; kept safe
        if (!(xdup && kx)) {
            const int   xf = kx ? fx1 : fx0;
            const float xw = xdup ? 1.f : (kx ? fxw : 1.f - fxw);
            #pragma unroll
            for (int kz = 0; kz < 2; ++kz) {
                int cell = (ky*X_FOOT + xf)*VZZ + (kz ? z1 : z0);
                int v = idx_lds[cell];
                if (v >= 0)
                    P_lds[sl*PSTR + v] = f2bf(ywp * xw * (kz ? fzw : 1.f - fzw));
            }
        }
    }

    // ---------- Phase 2c: stage bev -> x_lds[s][0..79] ----------
    #pragma unroll
    for (int j5 = 0; j5 < 5; ++j5) {
        ushort4 pk = make_ushort4(f2bf(bvv[j5*4+0]), f2bf(bvv[j5*4+1]),
                                  f2bf(bvv[j5*4+2]), f2bf(bvv[j5*4+3]));
        *(ushort4*)&x_lds[sl*RS + quarter*20 + j5*4] = pk;
    }

    // ---------- Phase 2d: commit feats rows transposed -> Rt[c][slot] ----------
    // All 64 slot-columns [0,64) covered: real rows for slot<nst, zeros for the
    // K-pad gap (so MFMA's k in [0,64) never reads garbage/NaN).
    {
        ushort vals[20];
        #pragma unroll
        for (int q = 0; q < 5; ++q) {
            vals[4*q+0] = rowact ? f2bf(rbuf[q].x) : (ushort)0;
            vals[4*q+1] = rowact ? f2bf(rbuf[q].y) : (ushort)0;
            vals[4*q+2] = rowact ? f2bf(rbuf[q].z) : (ushort)0;
            vals[4*q+3] = rowact ? f2bf(rbuf[q].w) : (ushort)0;
        }
        #pragma unroll
        for (int e = 0; e < 20; ++e)
            Rt_lds[(part*20 + e)*PSTR + myslot] = vals[e];
    }
    bar_lgkm();

    // ---------- Phase 3: prior = Rt x P^T via MFMA -> x_lds[s][80..159] ----------
    const int lrow = lane & 15, lgrp = lane >> 4;
    {
        const int prow = (wv*16 + lrow)*PSTR;
        s16x8 p0 = *(const s16x8*)&P_lds[prow +      lgrp*8];
        s16x8 p1 = *(const s16x8*)&P_lds[prow + 32 + lgrp*8];
        #pragma unroll
        for (int mt = 0; mt < 5; ++mt) {
            const int arow = (mt*16 + lrow)*PSTR;
            s16x8 a0 = *(const s16x8*)&Rt_lds[arow +      lgrp*8];
            s16x8 a1 = *(const s16x8*)&Rt_lds[arow + 32 + lgrp*8];
            f32x4 pa = (f32x4){0.f, 0.f, 0.f, 0.f};
            pa = __builtin_amdgcn_mfma_f32_16x16x32_bf16(a0, p0, pa, 0, 0, 0);
            pa = __builtin_amdgcn_mfma_f32_16x16x32_bf16(a1, p1, pa, 0, 0, 0);
            // D: col = lane&15 = s_local, row = c = mt*16 + lgrp*4 + r
            ushort4 pk = make_ushort4(f2bf(pa[0]), f2bf(pa[1]),
                                      f2bf(pa[2]), f2bf(pa[3]));
            *(ushort4*)&x_lds[(wv*16 + lrow)*RS + 80 + mt*16 + lgrp*4] = pk;
        }
    }

    // ---------- Overflow fallback (block-uniform, ~never taken) ----------
    if (nstot > SLOTS) {
        bar_lgkm();
        float add20[20];
        #pragma unroll
        for (int j = 0; j < 20; ++j) add20[j] = 0.f;
        bool any = false;
        #pragma unroll
        for (int k = 0; k < 8; ++k) {
            int kz = k & 1, kx = (k>>1)&1, ky = k>>2;
            int cell = (ky*X_FOOT + (kx ? fx1 : fx0))*VZZ + (kz ? z1 : z0);
            int v = idx_lds[cell];
            if (v < -1) {
                any = true;
                float wtk = (ky?fy:1.f-fy) * (kx?fxw:1.f-fxw) * (kz?fzw:1.f-fzw);
                const float4* p = feats4 + (-v - 2)*20 + quarter*5;
                #pragma unroll
                for (int q = 0; q < 5; ++q) {
                    float4 f = p[q];
                    add20[4*q]   += wtk*f.x; add20[4*q+1] += wtk*f.y;
                    add20[4*q+2] += wtk*f.z; add20[4*q+3] += wtk*f.w;
                }
            }
        }
        if (any) {
            #pragma unroll
            for (int q = 0; q < 5; ++q) {
                ushort* dst = &x_lds[sl*RS + 80 + quarter*20 + q*4];
                ushort4 old = *(ushort4*)dst;
                const ushort ov[4] = {old.x, old.y, old.z, old.w};
                ushort nv[4];
                #pragma unroll
                for (int e = 0; e < 4; ++e) {
                    float f = __builtin_bit_cast(float, (uint)ov[e] << 16) + add20[4*q+e];
                    nv[e] = f2bf(f);
                }
                *(ushort4*)dst = make_ushort4(nv[0], nv[1], nv[2], nv[3]);
            }
        }
    }
    bar_lgkm();

    // ---------- Phase D: MFMA GEMM  y[o][s] = sum_c W[o][c] * x[c][s] ----------
    f32x4 acc[5];
    #pragma unroll
    for (int mt = 0; mt < 5; ++mt) acc[mt] = (f32x4){0.f, 0.f, 0.f, 0.f};

    const int srow = (wv*16 + lrow) * RS;   // each wave owns a 16-s tile

    #pragma unroll
    for (int ks = 0; ks < 5; ++ks) {
        s16x8 b = *(const s16x8*)&x_lds[srow + ks*32 + lgrp*8];
        #pragma unroll
        for (int mt = 0; mt < 5; ++mt) {
            s16x8 a = *(const s16x8*)&wfrag[((mt*5 + ks)*64 + lane)*8];
            acc[mt] = __builtin_amdgcn_mfma_f32_16x16x32_bf16(a, b, acc[mt], 0, 0, 0);
        }
    }

    // ---------- Epilogue: BN + residual (batched b64 LDS read) + ReLU ----------
    const int slocal = wv*16 + lrow;
    const int sglob  = sbase + slocal;
    #pragma unroll
    for (int mt = 0; mt < 5; ++mt) {
        ushort4 rr = *(const ushort4*)&x_lds[slocal*RS + mt*16 + lgrp*4];
        const ushort rrv[4] = {rr.x, rr.y, rr.z, rr.w};
        #pragma unroll
        for (int r = 0; r < 4; ++r) {
            int o = mt*16 + lgrp*4 + r;
            float2 ss = bnss[o];
            float resid = __builtin_bit_cast(float, (uint)rrv[r] << 16);
            float v = acc[mt][r]*ss.x + ss.y + resid;
            out[o*SPATIAL + sglob] = fmaxf(v, 0.f);
        }
    }
}

extern "C" void kernel_launch(void* const* d_in, const int* in_sizes, int n_in,
                              void* d_out, int out_size, void* d_ws, size_t ws_size,
                              hipStream_t stream) {
    const float* bev    = (const float*)d_in[0];
    const int*   coords = (const int*)  d_in[1];
    const float* feats  = (const float*)d_in[2];
    const float* wconv  = (const float*)d_in[3];
    const float* bconv  = (const float*)d_in[4];
    const float* gamma  = (const float*)d_in[5];
    const float* beta   = (const float*)d_in[6];
    const float* mean   = (const float*)d_in[7];
    const float* var    = (const float*)d_in[8];
    float*       out    = (float*)d_out;

    int*    winner = (int*)d_ws;                                      // 5,242,880 B
    ushort* wfrag  = (ushort*)((char*)d_ws + (size_t)NVOX*4);         // 25,600 B
    float2* bnss   = (float2*)((char*)d_ws + (size_t)NVOX*4 + 25600); // 640 B
    int npts = in_sizes[1] / 4;

    hipLaunchKernelGGL(setup_k, dim3(1331), dim3(256), 0, stream,
                       wconv, bconv, gamma, beta, mean, var,
                       (int4*)winner, wfrag, bnss);
    hipLaunchKernelGGL(scatter_k, dim3((npts + 255)/256), dim3(256), 0, stream,
                       coords, npts, winner);
    hipLaunchKernelGGL(fused_k, dim3(NWG), dim3(256), 0, stream,
                       bev, feats, winner, wfrag, bnss, out);
}